// Round 1
// baseline (292.092 us; speedup 1.0000x reference)
//
#include <hip/hip_runtime.h>
#include <hip/hip_bf16.h>

// MoE: N=16384 tokens, D=1024, E=8 experts, top-2 routing.
// Strategy: route first (top-2 only = 68.7 GFLOP vs 275 dense), grouped
// gathered bf16 MFMA GEMM per expert, slot-buffer combine (no atomics).

constexpr int DIMS = 1024;
constexpr int NE   = 8;

typedef __attribute__((ext_vector_type(8))) short short8;
typedef __attribute__((ext_vector_type(4))) float f32x4;

typedef const __attribute__((address_space(1))) void* gp_t;
typedef __attribute__((address_space(3))) void* sp_t;

__device__ __forceinline__ float b2f(unsigned short u) {
  union { unsigned int i; float f; } x; x.i = ((unsigned)u) << 16; return x.f;
}

// ---------------- expert_w fp32 -> bf16 ----------------
__global__ __launch_bounds__(256) void wconv_kernel(const float* __restrict__ w,
                                                    __hip_bfloat16* __restrict__ wb) {
  size_t i = (size_t)blockIdx.x * 256 + threadIdx.x;  // 8 elements per thread
  const float4* w4 = (const float4*)w;
  float4 a = w4[i * 2], b = w4[i * 2 + 1];
  union { __hip_bfloat16 h[8]; float4 f; } u;
  u.h[0] = __float2bfloat16(a.x); u.h[1] = __float2bfloat16(a.y);
  u.h[2] = __float2bfloat16(a.z); u.h[3] = __float2bfloat16(a.w);
  u.h[4] = __float2bfloat16(b.x); u.h[5] = __float2bfloat16(b.y);
  u.h[6] = __float2bfloat16(b.z); u.h[7] = __float2bfloat16(b.w);
  ((float4*)wb)[i] = u.f;
}

// ---------------- router: logits, top-2, dispatch, x->bf16 ----------------
// 16 tokens per block (wave-per-token, 4 iters/wave), 1024 blocks.
__global__ __launch_bounds__(256) void router_kernel(
    const float* __restrict__ x, const float* __restrict__ rw,
    const float* __restrict__ rb, __hip_bfloat16* __restrict__ xb,
    int* __restrict__ counts, int* __restrict__ entries,
    float* __restrict__ gates, int n_tok) {
  __shared__ float s_rw[NE * DIMS];   // 32 KB
  __shared__ int s_cnt[NE], s_base[NE];
  __shared__ int s_e[32];
  __shared__ float s_g[32];
  __shared__ int s_pos[32];
  const int tid = threadIdx.x;

  const float4* rw4 = (const float4*)rw;
  float4* s4 = (float4*)s_rw;
  for (int i = tid; i < NE * DIMS / 4; i += 256) s4[i] = rw4[i];
  if (tid < NE) s_cnt[tid] = 0;
  __syncthreads();

  const int wave = tid >> 6, lane = tid & 63;
  for (int i = 0; i < 4; ++i) {
    int t = blockIdx.x * 16 + wave * 4 + i;
    float a[NE];
#pragma unroll
    for (int e = 0; e < NE; ++e) a[e] = 0.f;
#pragma unroll
    for (int j = 0; j < DIMS / 64; ++j) {
      int d = lane + j * 64;
      float v = x[(size_t)t * DIMS + d];
      xb[(size_t)t * DIMS + d] = __float2bfloat16(v);
#pragma unroll
      for (int e = 0; e < NE; ++e) a[e] = fmaf(v, s_rw[e * DIMS + d], a[e]);
    }
    // double-precision butterfly reduce (minimize top-2 tie-flip risk)
    double da[NE];
#pragma unroll
    for (int e = 0; e < NE; ++e) da[e] = (double)a[e];
#pragma unroll
    for (int off = 32; off > 0; off >>= 1) {
#pragma unroll
      for (int e = 0; e < NE; ++e) da[e] += __shfl_xor(da[e], off, 64);
    }
    if (lane == 0) {
      float l[NE];
#pragma unroll
      for (int e = 0; e < NE; ++e) l[e] = (float)da[e] + rb[e];
      int e0 = 0;
#pragma unroll
      for (int e = 1; e < NE; ++e) if (l[e] > l[e0]) e0 = e;
      int e1 = (e0 == 0) ? 1 : 0;
#pragma unroll
      for (int e = 0; e < NE; ++e) if (e != e0 && l[e] > l[e1]) e1 = e;
      // renormalized top-2 softmax gates = sigmoid of logit gap
      float r = expf(l[e1] - l[e0]);   // <= 1
      float g0 = 1.f / (1.f + r);
      float g1 = 1.f - g0;
      int ai = (wave * 4 + i) * 2;
      int p0 = atomicAdd(&s_cnt[e0], 1);
      int p1 = atomicAdd(&s_cnt[e1], 1);
      s_e[ai] = e0; s_g[ai] = g0; s_pos[ai] = p0;
      s_e[ai + 1] = e1; s_g[ai + 1] = g1; s_pos[ai + 1] = p1;
    }
  }
  __syncthreads();
  if (tid < NE) s_base[tid] = atomicAdd(&counts[tid], s_cnt[tid]);
  __syncthreads();
  if (tid < 32) {
    int e = s_e[tid];
    int p = s_base[e] + s_pos[tid];
    int tok = blockIdx.x * 16 + (tid >> 1);
    entries[e * n_tok + p] = (tok << 1) | (tid & 1);  // token*2 + slot
    gates[e * n_tok + p] = s_g[tid];
  }
}

// ---------------- grouped gathered GEMM (m97 structure) ----------------
// 128x128 tile, BK=32, 4 waves x (4x4 of mfma_f32_16x16x32_bf16).
__global__ __launch_bounds__(256) void moe_gemm(
    const __hip_bfloat16* __restrict__ xb, const __hip_bfloat16* __restrict__ wb,
    const float* __restrict__ eb, const int* __restrict__ counts,
    const int* __restrict__ entries, const float* __restrict__ gates,
    __hip_bfloat16* __restrict__ y, int n_tok) {
  // map blockIdx.y -> (expert, row-tile) from device-side counts (fixed grid)
  int e = -1, rt = 0, cnt = 0, acc_t = 0;
#pragma unroll
  for (int i = 0; i < NE; ++i) {
    int c = counts[i];
    int t = (c + 127) >> 7;
    if (e < 0 && (int)blockIdx.y < acc_t + t) { e = i; rt = (int)blockIdx.y - acc_t; cnt = c; }
    acc_t += t;
  }
  if (e < 0) return;

  __shared__ __hip_bfloat16 As[128 * 32];  // 8 KB, dense (global_load_lds)
  __shared__ __hip_bfloat16 Bs[128 * 32];  // 8 KB

  const int tid = threadIdx.x;
  const int lane = tid & 63, wave = tid >> 6;
  const int row0 = rt * 128;
  const int n0 = blockIdx.x * 128;

  // staging: chunk c = 16B; row = c>>2, kcol = (c&3)*8; thread t owns chunks t, t+256
  const int rA0 = tid >> 2, rA1 = rA0 + 64;
  const int kcol = (tid & 3) * 8;
  int gr0 = row0 + rA0, gr1 = row0 + rA1;
  int ent0 = (gr0 < cnt) ? entries[e * n_tok + gr0] : 0;
  int ent1 = (gr1 < cnt) ? entries[e * n_tok + gr1] : 0;
  const __hip_bfloat16* ap0 = xb + (size_t)(ent0 >> 1) * DIMS + kcol;
  const __hip_bfloat16* ap1 = xb + (size_t)(ent1 >> 1) * DIMS + kcol;
  const __hip_bfloat16* wbase = wb + (size_t)e * DIMS * DIMS;
  const __hip_bfloat16* bp0 = wbase + (size_t)(n0 + rA0) * DIMS + kcol;
  const __hip_bfloat16* bp1 = wbase + (size_t)(n0 + rA1) * DIMS + kcol;
  __hip_bfloat16* sA0 = As + tid * 8;
  __hip_bfloat16* sA1 = As + (tid + 256) * 8;
  __hip_bfloat16* sB0 = Bs + tid * 8;
  __hip_bfloat16* sB1 = Bs + (tid + 256) * 8;

  f32x4 acc[4][4] = {};

  const int wm = (wave & 1) * 64, wn = (wave >> 1) * 64;
  const int fr = lane & 15, fko = (lane >> 4) * 8;

  for (int k0 = 0; k0 < DIMS; k0 += 32) {
    __builtin_amdgcn_global_load_lds((gp_t)(ap0 + k0), (sp_t)sA0, 16, 0, 0);
    __builtin_amdgcn_global_load_lds((gp_t)(ap1 + k0), (sp_t)sA1, 16, 0, 0);
    __builtin_amdgcn_global_load_lds((gp_t)(bp0 + k0), (sp_t)sB0, 16, 0, 0);
    __builtin_amdgcn_global_load_lds((gp_t)(bp1 + k0), (sp_t)sB1, 16, 0, 0);
    __syncthreads();
    short8 af[4], bf[4];
#pragma unroll
    for (int mt = 0; mt < 4; ++mt)
      af[mt] = *(const short8*)&As[(wm + mt * 16 + fr) * 32 + fko];
#pragma unroll
    for (int nt = 0; nt < 4; ++nt)
      bf[nt] = *(const short8*)&Bs[(wn + nt * 16 + fr) * 32 + fko];
#pragma unroll
    for (int mt = 0; mt < 4; ++mt)
#pragma unroll
      for (int nt = 0; nt < 4; ++nt)
        acc[mt][nt] = __builtin_amdgcn_mfma_f32_16x16x32_bf16(af[mt], bf[nt], acc[mt][nt], 0, 0, 0);
    __syncthreads();
  }

  // epilogue: C/D layout col=lane&15, row=(lane>>4)*4+reg. Store gated y (bf16).
  const int quad = lane >> 4;
  float bias[4];
#pragma unroll
  for (int nt = 0; nt < 4; ++nt) bias[nt] = eb[e * DIMS + n0 + wn + nt * 16 + fr];
#pragma unroll
  for (int mt = 0; mt < 4; ++mt) {
#pragma unroll
    for (int r = 0; r < 4; ++r) {
      int m = wm + mt * 16 + quad * 4 + r;
      int gr = row0 + m;
      if (gr < cnt) {
        int ent = entries[e * n_tok + gr];
        float g = gates[e * n_tok + gr];
        __hip_bfloat16* yp = y + (size_t)ent * DIMS + n0 + wn + fr;
#pragma unroll
        for (int nt = 0; nt < 4; ++nt)
          yp[nt * 16] = __float2bfloat16(g * (acc[mt][nt][r] + bias[nt]));
      }
    }
  }
}

// ---------------- combine: out[n] = y[n,0] + y[n,1] ----------------
__global__ __launch_bounds__(256) void combine_kernel(const __hip_bfloat16* __restrict__ y,
                                                      float* __restrict__ out) {
  size_t idx = (size_t)blockIdx.x * 256 + threadIdx.x;  // one 8-wide chunk
  size_t n = idx >> 7;
  int c = (int)(idx & 127) << 3;
  short8 v0 = *(const short8*)(y + (n * 2) * DIMS + c);
  short8 v1 = *(const short8*)(y + (n * 2 + 1) * DIMS + c);
  float4 o0, o1;
  o0.x = b2f((unsigned short)v0[0]) + b2f((unsigned short)v1[0]);
  o0.y = b2f((unsigned short)v0[1]) + b2f((unsigned short)v1[1]);
  o0.z = b2f((unsigned short)v0[2]) + b2f((unsigned short)v1[2]);
  o0.w = b2f((unsigned short)v0[3]) + b2f((unsigned short)v1[3]);
  o1.x = b2f((unsigned short)v0[4]) + b2f((unsigned short)v1[4]);
  o1.y = b2f((unsigned short)v0[5]) + b2f((unsigned short)v1[5]);
  o1.z = b2f((unsigned short)v0[6]) + b2f((unsigned short)v1[6]);
  o1.w = b2f((unsigned short)v0[7]) + b2f((unsigned short)v1[7]);
  float* op = out + n * DIMS + c;
  ((float4*)op)[0] = o0;
  ((float4*)op)[1] = o1;
}

extern "C" void kernel_launch(void* const* d_in, const int* in_sizes, int n_in,
                              void* d_out, int out_size, void* d_ws, size_t ws_size,
                              hipStream_t stream) {
  const float* x  = (const float*)d_in[0];
  const float* rw = (const float*)d_in[1];
  const float* rb = (const float*)d_in[2];
  const float* ew = (const float*)d_in[3];
  const float* eb = (const float*)d_in[4];
  float* out = (float*)d_out;
  const int n_tok = in_sizes[0] / DIMS;  // 16384

  // workspace layout
  char* ws = (char*)d_ws;
  size_t off = 0;
  int* counts = (int*)ws;                      off += 256;
  __hip_bfloat16* xb = (__hip_bfloat16*)(ws + off); off += (size_t)n_tok * DIMS * 2;
  __hip_bfloat16* wb = (__hip_bfloat16*)(ws + off); off += (size_t)NE * DIMS * DIMS * 2;
  int*   entries = (int*)(ws + off);           off += (size_t)NE * n_tok * 4;
  float* gates   = (float*)(ws + off);         off += (size_t)NE * n_tok * 4;
  __hip_bfloat16* y = (__hip_bfloat16*)(ws + off); off += (size_t)n_tok * 2 * DIMS * 2;
  if (ws_size < off) return;  // signature: output stays exactly zero

  hipMemsetAsync(counts, 0, 256, stream);
  wconv_kernel<<<NE * DIMS * DIMS / (8 * 256), 256, 0, stream>>>(ew, wb);
  router_kernel<<<n_tok / 16, 256, 0, stream>>>(x, rw, rb, xb, counts, entries, gates, n_tok);
  dim3 g(DIMS / 128, 2 * n_tok / 128 + NE);
  moe_gemm<<<g, 256, 0, stream>>>(xb, wb, eb, counts, entries, gates, y, n_tok);
  combine_kernel<<<(unsigned)((size_t)n_tok * DIMS / 8 / 256), 256, 0, stream>>>(y, out);
}